// Round 1
// baseline (127.812 us; speedup 1.0000x reference)
//
#include <hip/hip_runtime.h>

// Problem constants (from reference): B=32, N=4096, C=1152, K = int(N*0.1) = 409
#define B_ 32
#define N_ 4096
#define C_ 1152
#define K_ 409

// Kernel 1: absS[b*N+n] = |dot(feature[b,n,:], W) + bias|
// One wave (64 lanes) per patch; 4 waves per 256-thread block.
__global__ __launch_bounds__(256) void score_abs_kernel(
    const float* __restrict__ feat, const float* __restrict__ W,
    const float* __restrict__ bias, float* __restrict__ absS) {
  __shared__ float4 Ws[C_ / 4];  // 288 float4 = 4.5 KB
  for (int i = threadIdx.x; i < C_ / 4; i += 256)
    Ws[i] = reinterpret_cast<const float4*>(W)[i];
  __syncthreads();

  const int wave = threadIdx.x >> 6;
  const int lane = threadIdx.x & 63;
  const int patch = blockIdx.x * 4 + wave;  // grid sized exactly: always valid

  const float4* f4 = reinterpret_cast<const float4*>(feat) + (size_t)patch * (C_ / 4);
  float acc = 0.f;
#pragma unroll
  for (int j = 0; j < 4; ++j) {
    float4 a = f4[lane + j * 64];
    float4 w = Ws[lane + j * 64];
    acc += a.x * w.x + a.y * w.y + a.z * w.z + a.w * w.w;
  }
  if (lane < 32) {  // remaining 288-256=32 float4
    float4 a = f4[256 + lane];
    float4 w = Ws[256 + lane];
    acc += a.x * w.x + a.y * w.y + a.z * w.z + a.w * w.w;
  }
#pragma unroll
  for (int off = 32; off > 0; off >>= 1)
    acc += __shfl_down(acc, off, 64);
  if (lane == 0) absS[patch] = fabsf(acc + bias[0]);
}

// Kernel 2: per batch row, exact mean of top-K absolute scores.
// One block (256 threads) per row. Radix-select the K-th largest over the
// float bit pattern (all values >= 0 so uint32 order == float order).
__global__ __launch_bounds__(256) void topk_mean_kernel(
    const float* __restrict__ absS, float* __restrict__ out) {
  __shared__ float vals[N_];   // 16 KB
  __shared__ unsigned s_red[4];
  __shared__ float s_redf[4];

  const int b = blockIdx.x;
  const int wv = threadIdx.x >> 6;
  const int ln = threadIdx.x & 63;
  const float* row = absS + (size_t)b * N_;
  for (int i = threadIdx.x; i < N_; i += 256) vals[i] = row[i];
  __syncthreads();

  // Radix select: find bit pattern of the K-th largest value.
  unsigned prefix = 0;
  int k = K_;
  for (int bit = 31; bit >= 0; --bit) {
    const unsigned high_mask = (bit == 31) ? 0u : (0xFFFFFFFFu << (bit + 1));
    unsigned cnt = 0;
    for (int i = threadIdx.x; i < N_; i += 256) {
      unsigned e = __float_as_uint(vals[i]);
      if ((e & high_mask) == (prefix & high_mask) && ((e >> bit) & 1u)) cnt++;
    }
#pragma unroll
    for (int off = 32; off > 0; off >>= 1)
      cnt += __shfl_down(cnt, off, 64);
    if (ln == 0) s_red[wv] = cnt;
    __syncthreads();
    const unsigned total = s_red[0] + s_red[1] + s_red[2] + s_red[3];
    __syncthreads();
    if ((int)total >= k) prefix |= (1u << bit);
    else k -= (int)total;
  }
  const float thr = __uint_as_float(prefix);

  // Sum of elements strictly greater than thr, plus count; ties filled at thr.
  float sum = 0.f;
  unsigned cgt = 0;
  for (int i = threadIdx.x; i < N_; i += 256) {
    float v = vals[i];
    if (v > thr) { sum += v; cgt++; }
  }
#pragma unroll
  for (int off = 32; off > 0; off >>= 1) {
    sum += __shfl_down(sum, off, 64);
    cgt += __shfl_down(cgt, off, 64);
  }
  if (ln == 0) { s_red[wv] = cgt; s_redf[wv] = sum; }
  __syncthreads();
  if (threadIdx.x == 0) {
    const unsigned cg = s_red[0] + s_red[1] + s_red[2] + s_red[3];
    const float sg = s_redf[0] + s_redf[1] + s_redf[2] + s_redf[3];
    const float total = sg + (float)(K_ - (int)cg) * thr;
    out[b] = total / (float)K_;
  }
}

extern "C" void kernel_launch(void* const* d_in, const int* in_sizes, int n_in,
                              void* d_out, int out_size, void* d_ws, size_t ws_size,
                              hipStream_t stream) {
  const float* feat = (const float*)d_in[0];
  const float* W = (const float*)d_in[1];
  const float* bias = (const float*)d_in[2];
  float* out = (float*)d_out;
  float* absS = (float*)d_ws;  // B*N floats = 512 KB

  score_abs_kernel<<<(B_ * N_) / 4, 256, 0, stream>>>(feat, W, bias, absS);
  topk_mean_kernel<<<B_, 256, 0, stream>>>(absS, out);
}

// Round 2
// 108.241 us; speedup vs baseline: 1.1808x; 1.1808x over previous
//
#include <hip/hip_runtime.h>

// Problem constants: B=32, N=4096, C=1152, K = int(N*0.1) = 409
#define B_ 32
#define N_ 4096
#define C_ 1152
#define K_ 409

#define NBLK 2048
#define PATCH_PER_BLK ((B_ * N_) / NBLK)  // 64
#define ITERS (PATCH_PER_BLK / 4)         // 16

typedef float f32x4 __attribute__((ext_vector_type(4)));

// Kernel 1: absS[p] = |dot(feature[p,:], W) + bias| for p in [0, B*N).
// 2048 blocks; each block owns a contiguous 64-patch chunk (one wave per
// patch, 4 patches per iteration, 16 iterations). W cached in registers.
__global__ __launch_bounds__(256) void score_abs_kernel(
    const float* __restrict__ feat, const float* __restrict__ W,
    const float* __restrict__ bias, float* __restrict__ absS) {
  __shared__ f32x4 Ws[C_ / 4];  // 288 float4 = 4.5 KB
  for (int i = threadIdx.x; i < C_ / 4; i += 256)
    Ws[i] = reinterpret_cast<const f32x4*>(W)[i];
  __syncthreads();

  const int wave = threadIdx.x >> 6;
  const int lane = threadIdx.x & 63;
  const float b0 = bias[0];

  // Per-lane W fragments held in registers across all 16 iterations.
  const f32x4 w0 = Ws[lane];
  const f32x4 w1 = Ws[lane + 64];
  const f32x4 w2 = Ws[lane + 128];
  const f32x4 w3 = Ws[lane + 192];
  const f32x4 w4 = (lane < 32) ? Ws[lane + 256] : (f32x4)0.f;

  const int patch_base = blockIdx.x * PATCH_PER_BLK + wave;
#pragma unroll 4
  for (int it = 0; it < ITERS; ++it) {
    const int patch = patch_base + it * 4;
    const f32x4* f4 = reinterpret_cast<const f32x4*>(feat) + (size_t)patch * (C_ / 4);
    // Nontemporal: feature is a 604 MB one-shot stream, keep it out of L2/L3.
    f32x4 vacc = __builtin_nontemporal_load(&f4[lane]) * w0;
    vacc += __builtin_nontemporal_load(&f4[lane + 64]) * w1;
    vacc += __builtin_nontemporal_load(&f4[lane + 128]) * w2;
    vacc += __builtin_nontemporal_load(&f4[lane + 192]) * w3;
    if (lane < 32) vacc += __builtin_nontemporal_load(&f4[lane + 256]) * w4;
    float acc = vacc[0] + vacc[1] + vacc[2] + vacc[3];
#pragma unroll
    for (int off = 32; off > 0; off >>= 1)
      acc += __shfl_down(acc, off, 64);
    if (lane == 0) absS[patch] = fabsf(acc + b0);
  }
}

// Kernel 2: per batch row, exact mean of top-K absolute scores.
// Byte-wise radix select (4 passes, 256-bin LDS histogram + suffix scan).
// Valid because all values >= 0, so uint32 order == float order.
__global__ __launch_bounds__(256) void topk_mean_kernel(
    const float* __restrict__ absS, float* __restrict__ out) {
  __shared__ float vals[N_];        // 16 KB
  __shared__ unsigned hist[256];
  __shared__ unsigned cum[256];
  __shared__ unsigned s_sel[2];     // {selected byte, new k}
  __shared__ unsigned s_cred[4];
  __shared__ float s_sredf[4];

  const int t = threadIdx.x;
  const int wv = t >> 6;
  const int ln = t & 63;
  const int b = blockIdx.x;
  const float4* row4 = reinterpret_cast<const float4*>(absS + (size_t)b * N_);
  for (int i = t; i < N_ / 4; i += 256)
    reinterpret_cast<float4*>(vals)[i] = row4[i];
  __syncthreads();

  unsigned prefix = 0;
  unsigned k = K_;
#pragma unroll
  for (int p = 0; p < 4; ++p) {
    const int shift = 24 - 8 * p;
    const unsigned hmask = (p == 0) ? 0u : (0xFFFFFFFFu << (shift + 8));
    hist[t] = 0;
    __syncthreads();
    for (int i = t; i < N_; i += 256) {
      const unsigned e = __float_as_uint(vals[i]);
      if ((e & hmask) == (prefix & hmask))
        atomicAdd(&hist[(e >> shift) & 255u], 1u);
    }
    __syncthreads();
    // Suffix scan: cum[t] = sum_{j >= t} hist[j]  (Hillis–Steele, 8 steps)
    cum[t] = hist[t];
    __syncthreads();
#pragma unroll
    for (int off = 1; off < 256; off <<= 1) {
      const unsigned v = (t + off < 256) ? cum[t + off] : 0u;
      __syncthreads();
      cum[t] += v;
      __syncthreads();
    }
    // Select the largest byte value bv with cum[bv] >= k (exactly one thread).
    const unsigned cnt_ge = cum[t];
    const unsigned cnt_gt = (t == 255) ? 0u : cum[t + 1];
    if (cnt_ge >= k && cnt_gt < k) {
      s_sel[0] = (unsigned)t;
      s_sel[1] = k - cnt_gt;
    }
    __syncthreads();
    prefix |= s_sel[0] << shift;
    k = s_sel[1];
    __syncthreads();
  }
  const float thr = __uint_as_float(prefix);

  // Sum of elements strictly greater than thr; ties filled at thr.
  float sum = 0.f;
  unsigned cgt = 0;
  for (int i = t; i < N_; i += 256) {
    const float v = vals[i];
    if (v > thr) { sum += v; cgt++; }
  }
#pragma unroll
  for (int off = 32; off > 0; off >>= 1) {
    sum += __shfl_down(sum, off, 64);
    cgt += __shfl_down(cgt, off, 64);
  }
  if (ln == 0) { s_cred[wv] = cgt; s_sredf[wv] = sum; }
  __syncthreads();
  if (t == 0) {
    const unsigned cg = s_cred[0] + s_cred[1] + s_cred[2] + s_cred[3];
    const float sg = s_sredf[0] + s_sredf[1] + s_sredf[2] + s_sredf[3];
    out[b] = (sg + (float)(K_ - (int)cg) * thr) / (float)K_;
  }
}

extern "C" void kernel_launch(void* const* d_in, const int* in_sizes, int n_in,
                              void* d_out, int out_size, void* d_ws, size_t ws_size,
                              hipStream_t stream) {
  const float* feat = (const float*)d_in[0];
  const float* W = (const float*)d_in[1];
  const float* bias = (const float*)d_in[2];
  float* out = (float*)d_out;
  float* absS = (float*)d_ws;  // B*N floats = 512 KB

  score_abs_kernel<<<NBLK, 256, 0, stream>>>(feat, W, bias, absS);
  topk_mean_kernel<<<B_, 256, 0, stream>>>(absS, out);
}